// Round 5
// baseline (61.720 us; speedup 1.0000x reference)
//
#include <hip/hip_runtime.h>
#include <hip/hip_bf16.h>

typedef __attribute__((ext_vector_type(8))) short short8;
typedef __attribute__((ext_vector_type(4))) float f32x4;

#define OUT_DIM 11008
#define IN_DIM  4096
#define B_DIM   32
#define NROWS   32                 // W rows (output cols) per block
#define KSPL    8                  // K split across blocks
#define KPB     (IN_DIM / KSPL)    // 512 k per block
#define KCH     128                // k per staged chunk (512 B/row fp32)
#define NCH     (KPB / KCH)        // 4 chunks

__device__ __forceinline__ short8 cvt2(f32x4 f0, f32x4 f1) {
  short8 v;
  __hip_bfloat16 h;
  h = __float2bfloat16(f0[0]); v[0] = *reinterpret_cast<short*>(&h);
  h = __float2bfloat16(f0[1]); v[1] = *reinterpret_cast<short*>(&h);
  h = __float2bfloat16(f0[2]); v[2] = *reinterpret_cast<short*>(&h);
  h = __float2bfloat16(f0[3]); v[3] = *reinterpret_cast<short*>(&h);
  h = __float2bfloat16(f1[0]); v[4] = *reinterpret_cast<short*>(&h);
  h = __float2bfloat16(f1[1]); v[5] = *reinterpret_cast<short*>(&h);
  h = __float2bfloat16(f1[2]); v[6] = *reinterpret_cast<short*>(&h);
  h = __float2bfloat16(f1[3]); v[7] = *reinterpret_cast<short*>(&h);
  return v;
}

__device__ __forceinline__ short8 cvt8g(const float* __restrict__ src) {
  f32x4 f0 = *reinterpret_cast<const f32x4*>(src);
  f32x4 f1 = *reinterpret_cast<const f32x4*>(src + 4);
  return cvt2(f0, f1);
}

// W streamed through LDS via global_load_lds (linear dest, 512B-contiguous
// source segments, inverse-XOR-swizzled within 128B lines); fragments read
// from LDS with matching XOR (2-way banks = free), cvt fp32->bf16 in-reg.
// Hierarchical split-K: 8x across blocks, chunk k-halves across wave pairs.
__global__ __launch_bounds__(256, 4)
void bitnet_stream(const float* __restrict__ x,
                   const float* __restrict__ w,
                   const float* __restrict__ scale,
                   float* __restrict__ y)
{
  __shared__ float wlds[2][NROWS * KCH];   // 2 x 16 KB

  const int tid  = threadIdx.x;
  const int lane = tid & 63;
  const int wv   = tid >> 6;      // wave 0..3
  const int l15  = lane & 15;
  const int lg   = lane >> 4;     // 0..3
  const int nn   = wv & 1;        // wave's 16-row group
  const int kh   = wv >> 1;       // wave's k-half of each chunk
  const int obase = blockIdx.x * NROWS;
  const int k0    = blockIdx.y * KPB;

  // staging: flat byte = i*4096 + tid*16 -> row = flat>>9, slot16 = (flat>>4)&31
  const int srow  = tid >> 5;     // + i*8
  const int sslot = tid & 31;

  f32x4 acc[2];
  acc[0] = (f32x4){0.f, 0.f, 0.f, 0.f};
  acc[1] = (f32x4){0.f, 0.f, 0.f, 0.f};

  const int brow = nn * 16 + l15;         // B-frag LDS row
  const int bsw  = brow & 7;              // read-side XOR
  const float* xb = x + (size_t)l15 * IN_DIM + k0 + lg * 8;

  auto STAGE = [&](int c, int b) {
#pragma unroll
    for (int i = 0; i < 4; ++i) {
      const int row  = i * 8 + srow;
      const int slot = sslot ^ (row & 7);          // inverse swizzle on source
      const float* g = w + (size_t)(obase + row) * IN_DIM + k0 + c * KCH + slot * 4;
      const float* l = &wlds[b][i * 1024 + wv * 256];   // wave-uniform base
      __builtin_amdgcn_global_load_lds(
          (const __attribute__((address_space(1))) void*)g,
          (__attribute__((address_space(3))) void*)l, 16, 0, 0);
    }
  };

  auto COMPUTE = [&](int c, int b) {
#pragma unroll
    for (int s2 = 0; s2 < 2; ++s2) {
      const int s = kh * 2 + s2;                   // k-step 0..3 within chunk
      const int slot0 = (s * 8 + lg * 2 + 0) ^ bsw;
      const int slot1 = (s * 8 + lg * 2 + 1) ^ bsw;
      f32x4 b0 = *reinterpret_cast<const f32x4*>(&wlds[b][brow * KCH + slot0 * 4]);
      f32x4 b1 = *reinterpret_cast<const f32x4*>(&wlds[b][brow * KCH + slot1 * 4]);
      short8 bb = cvt2(b0, b1);
#pragma unroll
      for (int m = 0; m < 2; ++m) {
        short8 aa = cvt8g(xb + (size_t)m * 16 * IN_DIM + c * KCH + s * 32);
        acc[m] = __builtin_amdgcn_mfma_f32_16x16x32_bf16(aa, bb, acc[m], 0, 0, 0);
      }
    }
  };

  STAGE(0, 0);
  __syncthreads();
#pragma unroll
  for (int c = 0; c < NCH - 1; ++c) {
    STAGE(c + 1, (c + 1) & 1);    // next chunk in flight
    COMPUTE(c, c & 1);
    __syncthreads();              // publishes c+1, guards buf reuse
  }
  COMPUTE(NCH - 1, (NCH - 1) & 1);

  // epilogue: atomics into y (zeroed in-graph); rows = C/D row, col = lane&15
  const float sc = scale[0];
#pragma unroll
  for (int m = 0; m < 2; ++m)
#pragma unroll
    for (int r = 0; r < 4; ++r) {
      const int br = m * 16 + lg * 4 + r;
      const int o  = obase + nn * 16 + l15;
      atomicAdd(&y[(size_t)br * OUT_DIM + o], acc[m][r] * sc);
    }
}

extern "C" void kernel_launch(void* const* d_in, const int* in_sizes, int n_in,
                              void* d_out, int out_size, void* d_ws, size_t ws_size,
                              hipStream_t stream) {
  const float* x = (const float*)d_in[0];
  const float* w = (const float*)d_in[1];
  const float* s = (const float*)d_in[2];
  float* y = (float*)d_out;
  hipMemsetAsync(y, 0, (size_t)out_size * sizeof(float), stream);
  bitnet_stream<<<dim3(OUT_DIM / NROWS, KSPL), 256, 0, stream>>>(x, w, s, y);
}

// Round 6
// 54.734 us; speedup vs baseline: 1.1276x; 1.1276x over previous
//
#include <hip/hip_runtime.h>
#include <hip/hip_bf16.h>

typedef __attribute__((ext_vector_type(8))) short short8;
typedef __attribute__((ext_vector_type(4))) float f32x4;
typedef __attribute__((ext_vector_type(4))) unsigned int u32x4;

#define OUT_DIM 11008
#define IN_DIM  4096
#define B_DIM   32
#define WP_ROW  (IN_DIM / 4)                       // 1024 packed bytes per W row
#define WP_BYTES ((size_t)OUT_DIM * WP_ROW)        // 11,272,192

__device__ __forceinline__ short8 cvt8(const float* __restrict__ src) {
  f32x4 f0 = *reinterpret_cast<const f32x4*>(src);
  f32x4 f1 = *reinterpret_cast<const f32x4*>(src + 4);
  short8 v;
  __hip_bfloat16 h;
  h = __float2bfloat16(f0[0]); v[0] = *reinterpret_cast<short*>(&h);
  h = __float2bfloat16(f0[1]); v[1] = *reinterpret_cast<short*>(&h);
  h = __float2bfloat16(f0[2]); v[2] = *reinterpret_cast<short*>(&h);
  h = __float2bfloat16(f0[3]); v[3] = *reinterpret_cast<short*>(&h);
  h = __float2bfloat16(f1[0]); v[4] = *reinterpret_cast<short*>(&h);
  h = __float2bfloat16(f1[1]); v[5] = *reinterpret_cast<short*>(&h);
  h = __float2bfloat16(f1[2]); v[6] = *reinterpret_cast<short*>(&h);
  h = __float2bfloat16(f1[3]); v[7] = *reinterpret_cast<short*>(&h);
  return v;
}

// ---- Pass 1: streaming compress. W fp32 {-1,0,+1} -> 2-bit codes (plain
// k-order: byte = 4 consecutive w of one row). Reads are lane-dense 1KB/instr
// (m13 copy pattern); writes are dense 64B/instr byte stores. Also converts
// x -> bf16 in MFMA A-fragment layout. 2816 blocks = exactly 11 rounds/CU.
__global__ __launch_bounds__(256)
void pack_kernel(const float* __restrict__ x, const float* __restrict__ w,
                 unsigned char* __restrict__ wp, short* __restrict__ xf)
{
  const int wv   = threadIdx.x >> 6;
  const int lane = threadIdx.x & 63;
  const int task = blockIdx.x;
  if (task < OUT_DIM / 4) {
    const int r = task * 4 + wv;                   // one W row per wave
    const unsigned int* src = (const unsigned int*)w + (size_t)r * IN_DIM;
    unsigned char* dst = wp + (size_t)r * WP_ROW;
#pragma unroll 4
    for (int j = 0; j < 16; ++j) {                 // 16 x 1KB dense reads
      u32x4 u = *reinterpret_cast<const u32x4*>(src + j * 256 + lane * 4);
      unsigned int byte = 0;
#pragma unroll
      for (int e = 0; e < 4; ++e) {
        // +1.0f=0x3F800000 -> 01; -1.0f=0xBF800000 -> 11; 0 -> 00
        byte |= (((u[e] >> 23) & 1u) | ((u[e] >> 30) & 2u)) << (2 * e);
      }
      dst[j * 64 + lane] = (unsigned char)byte;    // dense 64B/instr
    }
  } else {
    const int q = (task - OUT_DIM / 4) * 4 + wv;   // 0..255 -> (t, m)
    const int t = q >> 1, m = q & 1;
    const int l15 = lane & 15, lg = lane >> 4;
    short8 v = cvt8(x + (size_t)(m * 16 + l15) * IN_DIM + t * 32 + lg * 8);
    // A-frag layout: xf[t][m][lane][8k] -> pass-2 loads 1KB contiguous/instr
    *reinterpret_cast<short8*>(xf + (size_t)t * 1024 + m * 512 + lane * 8) = v;
  }
}

// ---- Pass 2: GEMM from 11.3MB packed W (L2/L3-hot) + fragment-layout bf16 x.
// Byte -> 4 bf16 decode via 2KB LDS LUT. Block = 32 cols x k-half; 8 waves
// split the k-half; LDS combine + atomicAdd into y (y zeroed in-graph).
__global__ __launch_bounds__(512)
void gemm_kernel(const unsigned char* __restrict__ wp,
                 const short* __restrict__ xf,
                 const float* __restrict__ scale,
                 float* __restrict__ y)
{
  __shared__ unsigned int lut[512];          // 256 entries x uint2 (4 bf16)
  __shared__ float red[8][B_DIM][32];        // 32 KB k-combine

  const int tid = threadIdx.x;
  if (tid < 256) {                           // LUT init: byte -> 4 bf16
    unsigned int lo = 0, hi = 0;
#pragma unroll
    for (int e = 0; e < 4; ++e) {
      const unsigned int c = (tid >> (2 * e)) & 3u;
      const unsigned int h = ((c & 1u) ? 0x3F80u : 0u) | ((c & 2u) << 14);
      if (e < 2) lo |= h << (16 * e); else hi |= h << (16 * (e - 2));
    }
    lut[tid * 2] = lo; lut[tid * 2 + 1] = hi;
  }
  __syncthreads();

  const int lane = tid & 63;
  const int wv   = tid >> 6;                 // 0..7: k-16th within the k-half
  const int l15  = lane & 15;
  const int lg   = lane >> 4;
  const int o0   = blockIdx.x * 32;

  f32x4 acc[2][2];
#pragma unroll
  for (int c = 0; c < 2; ++c)
#pragma unroll
    for (int m = 0; m < 2; ++m)
      acc[c][m] = (f32x4){0.f, 0.f, 0.f, 0.f};

  const unsigned char* wrow0 = wp + (size_t)(o0 + l15) * WP_ROW;
  const unsigned char* wrow1 = wrow0 + (size_t)16 * WP_ROW;
  const int t0 = blockIdx.y * 64 + wv * 8;

#pragma unroll 4
  for (int i = 0; i < 8; ++i) {
    const int t = t0 + i;
    const int toff = t * 8 + lg * 2;
    const unsigned int s0 = *reinterpret_cast<const unsigned short*>(wrow0 + toff);
    const unsigned int s1 = *reinterpret_cast<const unsigned short*>(wrow1 + toff);
    union { short8 v; unsigned int u[4]; } b0, b1;
    b0.u[0] = lut[(s0 & 0xFFu) * 2];  b0.u[1] = lut[(s0 & 0xFFu) * 2 + 1];
    b0.u[2] = lut[(s0 >> 8) * 2];     b0.u[3] = lut[(s0 >> 8) * 2 + 1];
    b1.u[0] = lut[(s1 & 0xFFu) * 2];  b1.u[1] = lut[(s1 & 0xFFu) * 2 + 1];
    b1.u[2] = lut[(s1 >> 8) * 2];     b1.u[3] = lut[(s1 >> 8) * 2 + 1];
    short8 a0 = *reinterpret_cast<const short8*>(xf + (size_t)t * 1024 + lane * 8);
    short8 a1 = *reinterpret_cast<const short8*>(xf + (size_t)t * 1024 + 512 + lane * 8);
    acc[0][0] = __builtin_amdgcn_mfma_f32_16x16x32_bf16(a0, b0.v, acc[0][0], 0, 0, 0);
    acc[0][1] = __builtin_amdgcn_mfma_f32_16x16x32_bf16(a1, b0.v, acc[0][1], 0, 0, 0);
    acc[1][0] = __builtin_amdgcn_mfma_f32_16x16x32_bf16(a0, b1.v, acc[1][0], 0, 0, 0);
    acc[1][1] = __builtin_amdgcn_mfma_f32_16x16x32_bf16(a1, b1.v, acc[1][1], 0, 0, 0);
  }

  // wave partial -> LDS (C/D map: row = lg*4 + r, col = l15; proven in R1-R4)
#pragma unroll
  for (int c = 0; c < 2; ++c)
#pragma unroll
    for (int m = 0; m < 2; ++m)
#pragma unroll
      for (int r = 0; r < 4; ++r)
        red[wv][m * 16 + lg * 4 + r][c * 16 + l15] = acc[c][m][r];
  __syncthreads();

  const float sc = scale[0];
#pragma unroll
  for (int e = tid; e < B_DIM * 32; e += 512) {
    const int b  = e >> 5;
    const int oc = e & 31;
    float v = 0.f;
#pragma unroll
    for (int k = 0; k < 8; ++k) v += red[k][b][oc];
    atomicAdd(&y[(size_t)b * OUT_DIM + o0 + oc], v * sc);
  }
}

extern "C" void kernel_launch(void* const* d_in, const int* in_sizes, int n_in,
                              void* d_out, int out_size, void* d_ws, size_t ws_size,
                              hipStream_t stream) {
  const float* x = (const float*)d_in[0];
  const float* w = (const float*)d_in[1];
  const float* s = (const float*)d_in[2];
  float* y = (float*)d_out;
  unsigned char* wp = (unsigned char*)d_ws;                 // 11.27 MB packed W
  short* xf = (short*)((char*)d_ws + WP_BYTES);             // 256 KB bf16 x frags

  hipMemsetAsync(y, 0, (size_t)out_size * sizeof(float), stream);
  pack_kernel<<<dim3(OUT_DIM / 4 + 64), 256, 0, stream>>>(x, w, wp, xf);
  gemm_kernel<<<dim3(OUT_DIM / 32, 2), 512, 0, stream>>>(wp, xf, s, y);
}

// Round 7
// 42.007 us; speedup vs baseline: 1.4693x; 1.3030x over previous
//
#include <hip/hip_runtime.h>
#include <hip/hip_bf16.h>

typedef __attribute__((ext_vector_type(8))) short short8;
typedef __attribute__((ext_vector_type(4))) float f32x4;

#define OUT_DIM 11008
#define IN_DIM  4096
#define B_DIM   32
#define KSPL    16
#define KPB     (IN_DIM / KSPL)        // 256 k per split-K block
#define PART_ELEMS (B_DIM * OUT_DIM)   // 352256 floats per partial

__device__ __forceinline__ short8 cvt8(const float* __restrict__ src) {
  f32x4 f0 = *reinterpret_cast<const f32x4*>(src);
  f32x4 f1 = *reinterpret_cast<const f32x4*>(src + 4);
  short8 v;
  __hip_bfloat16 h;
  h = __float2bfloat16(f0[0]); v[0] = *reinterpret_cast<short*>(&h);
  h = __float2bfloat16(f0[1]); v[1] = *reinterpret_cast<short*>(&h);
  h = __float2bfloat16(f0[2]); v[2] = *reinterpret_cast<short*>(&h);
  h = __float2bfloat16(f0[3]); v[3] = *reinterpret_cast<short*>(&h);
  h = __float2bfloat16(f1[0]); v[4] = *reinterpret_cast<short*>(&h);
  h = __float2bfloat16(f1[1]); v[5] = *reinterpret_cast<short*>(&h);
  h = __float2bfloat16(f1[2]); v[6] = *reinterpret_cast<short*>(&h);
  h = __float2bfloat16(f1[3]); v[7] = *reinterpret_cast<short*>(&h);
  return v;
}

// R2 structure (best: 47.1us) with ONE change: the block's x-slice (32 rows x
// 256 k) is staged to LDS once as pre-converted bf16 A-fragments; the k-loop
// then does only 4 W-frag global loads + 2 ds_read_b128 + 8 MFMA per step.
// W fragments load directly from global (16 rows x 128B = full cache lines).
__global__ __launch_bounds__(256, 4)
void bitnet_partial(const float* __restrict__ x,
                    const float* __restrict__ w,
                    float* __restrict__ ws)
{
  // xl[t][m][lane*8 + j]: A-fragment octet for k-step t, frag m, lane
  __shared__ short xl[8][2][64 * 8];   // 16 KB

  const int tid  = threadIdx.x;
  const int lane = tid & 63;
  const int wv   = tid >> 6;       // wave 0..3
  const int l15  = lane & 15;
  const int lg   = lane >> 4;      // 0..3
  const int ow   = blockIdx.x * 256 + wv * 64;   // wave's output-col base
  const int k0   = blockIdx.y * KPB;

  // ---- stage x fragments once: 1024 octets, 256 threads x 4 ----
#pragma unroll
  for (int i = 0; i < 4; ++i) {
    const int o   = i * 256 + tid;
    const int t   = o >> 7;
    const int m   = (o >> 6) & 1;
    const int ln  = o & 63;
    const int row = m * 16 + (ln & 15);
    const int kof = t * 32 + (ln >> 4) * 8;
    short8 v = cvt8(x + (size_t)row * IN_DIM + k0 + kof);
    *reinterpret_cast<short8*>(&xl[t][m][ln * 8]) = v;
  }
  __syncthreads();

  f32x4 acc[2][4];
#pragma unroll
  for (int m = 0; m < 2; ++m)
#pragma unroll
    for (int n = 0; n < 4; ++n)
      acc[m][n] = (f32x4){0.f, 0.f, 0.f, 0.f};

  const float* wbase = w + (size_t)(ow + l15) * IN_DIM + k0 + lg * 8;

#pragma unroll 2
  for (int t = 0; t < KPB / 32; ++t) {
    const int kk = t * 32;
    short8 aa[2], bb[4];
    aa[0] = *reinterpret_cast<const short8*>(&xl[t][0][lane * 8]);
    aa[1] = *reinterpret_cast<const short8*>(&xl[t][1][lane * 8]);
#pragma unroll
    for (int n = 0; n < 4; ++n)
      bb[n] = cvt8(wbase + (size_t)n * 16 * IN_DIM + kk);
#pragma unroll
    for (int m = 0; m < 2; ++m)
#pragma unroll
      for (int n = 0; n < 4; ++n)
        acc[m][n] = __builtin_amdgcn_mfma_f32_16x16x32_bf16(aa[m], bb[n], acc[m][n], 0, 0, 0);
  }

  // partial store: ws[blockIdx.y][b][o], plain coalesced stores
  float* out = ws + (size_t)blockIdx.y * PART_ELEMS;
#pragma unroll
  for (int m = 0; m < 2; ++m)
#pragma unroll
    for (int n = 0; n < 4; ++n)
#pragma unroll
      for (int r = 0; r < 4; ++r) {
        const int brow = m * 16 + lg * 4 + r;   // C/D: row = (lane>>4)*4 + reg
        const int o    = ow + n * 16 + l15;     // col = lane&15
        out[(size_t)brow * OUT_DIM + o] = acc[m][n][r];
      }
}

// y[b][o] = scale * sum_{s<16} ws[s][b][o]
__global__ __launch_bounds__(256)
void bitnet_reduce(const float* __restrict__ ws,
                   const float* __restrict__ scale,
                   float* __restrict__ y)
{
  const size_t base = ((size_t)blockIdx.x * 256 + threadIdx.x) * 4;
  f32x4 s = (f32x4){0.f, 0.f, 0.f, 0.f};
#pragma unroll
  for (int i = 0; i < KSPL; ++i) {
    f32x4 v = *reinterpret_cast<const f32x4*>(ws + (size_t)i * PART_ELEMS + base);
    s += v;
  }
  const float sc = scale[0];
  s *= sc;
  *reinterpret_cast<f32x4*>(y + base) = s;
}

extern "C" void kernel_launch(void* const* d_in, const int* in_sizes, int n_in,
                              void* d_out, int out_size, void* d_ws, size_t ws_size,
                              hipStream_t stream) {
  const float* x = (const float*)d_in[0];
  const float* w = (const float*)d_in[1];
  const float* s = (const float*)d_in[2];
  float* y  = (float*)d_out;
  float* ws = (float*)d_ws;   // KSPL*PART_ELEMS*4 = 22.5 MB

  dim3 grid(OUT_DIM / 256, KSPL);   // 43 x 16 = 688 blocks, fully resident
  bitnet_partial<<<grid, 256, 0, stream>>>(x, w, ws);
  bitnet_reduce<<<PART_ELEMS / 1024, 256, 0, stream>>>(ws, s, y);
}